// Round 1
// baseline (425.429 us; speedup 1.0000x reference)
//
#include <hip/hip_runtime.h>

// ---------------------------------------------------------------------------
// SwinV2 WindowAttention fused pipeline (bf16 MFMA, fp32 accumulate)
//   Bw=256 windows, N=144 tokens, C=512, H=16 heads, hd=32, nW=64
// Pipeline: cvt(x,Wqkv,Wproj) -> cpb-mlp -> bias gather ->
//           GEMM qkv (bf16 out) -> attn (per b,h) -> GEMM proj (f32 out)
// ---------------------------------------------------------------------------

using f32x4  = __attribute__((ext_vector_type(4))) float;
using bf16x8 = __attribute__((ext_vector_type(8))) short;

__device__ __forceinline__ unsigned short f2bf(float f) {
  unsigned u = __float_as_uint(f);
  u = (u + 0x7fffu + ((u >> 16) & 1u)) >> 16;   // RNE
  return (unsigned short)u;
}
__device__ __forceinline__ float bf2f(unsigned short s) {
  return __uint_as_float(((unsigned)s) << 16);
}

typedef __attribute__((address_space(1))) unsigned int as1_u32;
typedef __attribute__((address_space(3))) unsigned int as3_u32;

__device__ __forceinline__ void gll16(const void* g, void* l) {
  // async global->LDS, 16B per lane; LDS dest must be wave-uniform base.
  __builtin_amdgcn_global_load_lds((const as1_u32*)g, (as3_u32*)l, 16, 0, 0);
}

// --------------------------- fp32 -> bf16 convert ---------------------------
__global__ void cvt_f32_bf16(const float4* __restrict__ in,
                             unsigned short* __restrict__ out, int n4) {
  int i = blockIdx.x * blockDim.x + threadIdx.x;
  int stride = gridDim.x * blockDim.x;
  for (; i < n4; i += stride) {
    float4 v = in[i];
    ushort4 o;
    o.x = f2bf(v.x); o.y = f2bf(v.y); o.z = f2bf(v.z); o.w = f2bf(v.w);
    *(ushort4*)(out + (size_t)i * 4) = o;
  }
}

// --------------------------- CPB MLP: tbl(529,16) ---------------------------
__global__ void cpb_mlp(const float* __restrict__ tbl_in,  // (529,2)
                        const float* __restrict__ w1,      // (512,2)
                        const float* __restrict__ b1,      // (512)
                        const float* __restrict__ w2,      // (16,512)
                        float* __restrict__ tbl_out) {     // (529,16)
  __shared__ float hid[512];
  const int p = blockIdx.x;
  const int t = threadIdx.x;
  float t0 = tbl_in[p * 2 + 0], t1 = tbl_in[p * 2 + 1];
  float hv = fmaf(w1[t * 2 + 0], t0, fmaf(w1[t * 2 + 1], t1, b1[t]));
  hid[t] = fmaxf(hv, 0.f);
  __syncthreads();
  const int head = t >> 5, j = t & 31;
  float partial = 0.f;
  for (int i = j; i < 512; i += 32) partial += hid[i] * w2[head * 512 + i];
#pragma unroll
  for (int mk = 16; mk >= 1; mk >>= 1) partial += __shfl_xor(partial, mk, 32);
  if (j == 0) tbl_out[p * 16 + head] = partial;
}

// ------------------- gather: bias_full[h][n][m] (16,144,144) ----------------
__global__ void bias_gather(const float* __restrict__ tbl,    // (529,16)
                            const int* __restrict__ idx,      // (144,144)
                            float* __restrict__ bias_full) {  // (16,20736)
  int f = blockIdx.x * 256 + threadIdx.x;
  if (f >= 16 * 20736) return;
  int h = f / 20736;
  int p = f - h * 20736;
  bias_full[f] = tbl[idx[p] * 16 + h];
}

// --------------------------- bf16 GEMM, C = A * B^T -------------------------
// A: [M][K] bf16 row-major, B: [N][K] bf16 row-major, K multiple of 32.
// 128x128 tile, 4 waves each owning 4x4 16x16 sub-tiles. m97 structure.
template <bool OUT_BF16>
__global__ __launch_bounds__(256) void gemm_bt_k(
    const unsigned short* __restrict__ A, const unsigned short* __restrict__ B,
    const float* __restrict__ bias, void* __restrict__ C, int N, int K) {
  __shared__ __align__(16) unsigned short As[128 * 32];
  __shared__ __align__(16) unsigned short Bs[128 * 32];
  const int tid = threadIdx.x;
  const int wave = tid >> 6, lane = tid & 63;
  const int m0 = blockIdx.y << 7, n0 = blockIdx.x << 7;
  const int wr = wave >> 1, wc = wave & 1;
  const int l15 = lane & 15, l4 = lane >> 4;

  f32x4 acc[4][4] = {};

  // per-lane global src (lane l -> row chunk + 16B column slice, matches
  // gload_lds's linear lane*16B LDS fill of a row-major [16][32] chunk)
  const unsigned short* gA = A + (size_t)(m0 + wave * 32 + (lane >> 2)) * K + (lane & 3) * 8;
  const unsigned short* gB = B + (size_t)(n0 + wave * 32 + (lane >> 2)) * K + (lane & 3) * 8;
  unsigned short* lA = As + wave * 32 * 32;  // wave-uniform LDS base
  unsigned short* lB = Bs + wave * 32 * 32;

  for (int k0 = 0; k0 < K; k0 += 32) {
    __syncthreads();
    gll16(gA + k0, lA);
    gll16(gA + k0 + (size_t)16 * K, lA + 16 * 32);
    gll16(gB + k0, lB);
    gll16(gB + k0 + (size_t)16 * K, lB + 16 * 32);
    __syncthreads();
    bf16x8 af[4], bfr[4];
#pragma unroll
    for (int t = 0; t < 4; ++t) {
      af[t]  = *(const bf16x8*)(As + (wr * 64 + t * 16 + l15) * 32 + l4 * 8);
      bfr[t] = *(const bf16x8*)(Bs + (wc * 64 + t * 16 + l15) * 32 + l4 * 8);
    }
#pragma unroll
    for (int i = 0; i < 4; ++i)
#pragma unroll
      for (int j = 0; j < 4; ++j)
        acc[i][j] = __builtin_amdgcn_mfma_f32_16x16x32_bf16(af[i], bfr[j], acc[i][j], 0, 0, 0);
  }

#pragma unroll
  for (int i = 0; i < 4; ++i) {
    int rowb = m0 + wr * 64 + i * 16 + l4 * 4;
#pragma unroll
    for (int j = 0; j < 4; ++j) {
      int col = n0 + wc * 64 + j * 16 + l15;
      float bv = bias[col];
#pragma unroll
      for (int r = 0; r < 4; ++r) {
        size_t off = (size_t)(rowb + r) * N + col;
        float v = acc[i][j][r] + bv;
        if (OUT_BF16) ((unsigned short*)C)[off] = f2bf(v);
        else          ((float*)C)[off] = v;
      }
    }
  }
}

// ------------------------------- attention ----------------------------------
// One block (256 thr, 4 waves) per (b, h). qkv: [36864][1536] bf16
// (cols 0-511=q, 512-1023=k, 1024-1535=v at h*32+d).
// LDS: Qs[144][40], Ks[144][40], SP[144][168]; Vt[32][168] overlays Qs.
__global__ __launch_bounds__(256) void attn_k(
    const unsigned short* __restrict__ qkv, const float* __restrict__ mask,
    const float* __restrict__ biasf, unsigned short* __restrict__ aout) {
  extern __shared__ __align__(16) char smem[];
  unsigned short* Qs = (unsigned short*)smem;             // 11520 B
  unsigned short* Ks = (unsigned short*)(smem + 11520);   // 11520 B
  unsigned short* SP = (unsigned short*)(smem + 23040);   // 48384 B
  unsigned short* Vt = (unsigned short*)smem;             // 10752 B overlay

  const int h = blockIdx.x, b = blockIdx.y;
  const int tid = threadIdx.x;
  const int wave = tid >> 6, lane = tid & 63;
  const int l15 = lane & 15, l4 = lane >> 4;
  const size_t base = (size_t)b * 144 * 1536;

  // ---- stage Q, K (16B chunks; row stride 40 avoids 8-way LDS conflicts)
  for (int c = tid; c < 1152; c += 256) {
    int which = (c >= 576) ? 1 : 0;
    int cc = which ? (c - 576) : c;
    int n = cc >> 2, part = cc & 3;
    uint4 v = *(const uint4*)(qkv + base + (size_t)n * 1536 + which * 512 + h * 32 + part * 8);
    unsigned short* dst = (which ? Ks : Qs) + n * 40 + part * 8;
    *(uint4*)dst = v;
  }
  __syncthreads();

  // ---- S = Q K^T  (raw, unscaled) -> SP bf16. 81 tiles of 16x16, K=32 exact.
  for (int tt = wave; tt < 81; tt += 4) {
    int ti = tt / 9, tj = tt - ti * 9;
    bf16x8 aq = *(const bf16x8*)(Qs + (ti * 16 + l15) * 40 + l4 * 8);
    bf16x8 bk = *(const bf16x8*)(Ks + (tj * 16 + l15) * 40 + l4 * 8);
    f32x4 c = {0.f, 0.f, 0.f, 0.f};
    c = __builtin_amdgcn_mfma_f32_16x16x32_bf16(aq, bk, c, 0, 0, 0);
    unsigned short* scol = SP + tj * 16 + l15;
#pragma unroll
    for (int r = 0; r < 4; ++r)
      scol[(ti * 16 + l4 * 4 + r) * 168] = f2bf(c[r]);
  }
  __syncthreads();

  // ---- stage V transposed into Vt (overlays Qs; Q dead now). Zero n-pad.
  for (int e = tid; e < 4608; e += 256) {
    int n = e >> 5, d = e & 31;
    Vt[d * 168 + n] = qkv[base + (size_t)n * 1536 + 1024 + h * 32 + d];
  }
  for (int e = tid; e < 768; e += 256) {
    int d = e / 24, n = 144 + (e - (e / 24) * 24);
    Vt[d * 168 + n] = 0;
  }

  // ---- softmax: 16 groups x 16 lanes; group g owns rows g, g+16, ..., g+128
  {
    const int g = tid >> 4, j = tid & 15;
    const float* mrow = mask + (size_t)(b & 63) * 20736;
    const float* brow = biasf + (size_t)h * 20736;
    const float sc = 0.17677669529663688f;  // hd^-0.5, hd=32
#pragma unroll
    for (int rr = 0; rr < 9; ++rr) {
      int r = g + rr * 16;
      float lv[9];
      float mx = -3.0e38f;
#pragma unroll
      for (int c2 = 0; c2 < 9; ++c2) {
        int m = j + c2 * 16;
        float s = bf2f(SP[r * 168 + m]);
        float l = fmaf(s, sc, mrow[r * 144 + m] + brow[r * 144 + m]);
        lv[c2] = l;
        mx = fmaxf(mx, l);
      }
#pragma unroll
      for (int mk = 8; mk >= 1; mk >>= 1) mx = fmaxf(mx, __shfl_xor(mx, mk, 16));
      float sum = 0.f;
#pragma unroll
      for (int c2 = 0; c2 < 9; ++c2) {
        lv[c2] = __expf(lv[c2] - mx);
        sum += lv[c2];
      }
#pragma unroll
      for (int mk = 8; mk >= 1; mk >>= 1) sum += __shfl_xor(sum, mk, 16);
      float inv = 1.f / sum;
#pragma unroll
      for (int c2 = 0; c2 < 9; ++c2)
        SP[r * 168 + j + c2 * 16] = f2bf(lv[c2] * inv);
      SP[r * 168 + 144 + j] = 0;  // zero K-pad cols 144..159
    }
  }
  __syncthreads();

  // ---- O = P V : 18 tiles (9 n-blocks x 2 d-blocks), K padded to 160.
  for (int tt = wave; tt < 18; tt += 4) {
    int ti = tt >> 1, dj = tt & 1;
    f32x4 c = {0.f, 0.f, 0.f, 0.f};
    const unsigned short* pa = SP + (ti * 16 + l15) * 168;
    const unsigned short* vb = Vt + (dj * 16 + l15) * 168;
#pragma unroll
    for (int ks = 0; ks < 5; ++ks) {
      bf16x8 ap = *(const bf16x8*)(pa + ks * 32 + l4 * 8);
      bf16x8 bv = *(const bf16x8*)(vb + ks * 32 + l4 * 8);
      c = __builtin_amdgcn_mfma_f32_16x16x32_bf16(ap, bv, c, 0, 0, 0);
    }
#pragma unroll
    for (int r = 0; r < 4; ++r) {
      int n = ti * 16 + l4 * 4 + r;
      int d = dj * 16 + l15;
      aout[((size_t)(b * 144 + n)) * 512 + h * 32 + d] = f2bf(c[r]);
    }
  }
}

// ------------------------------- launcher -----------------------------------
extern "C" void kernel_launch(void* const* d_in, const int* in_sizes, int n_in,
                              void* d_out, int out_size, void* d_ws, size_t ws_size,
                              hipStream_t stream) {
  const float* x        = (const float*)d_in[0];   // (256,144,512)
  const float* mask     = (const float*)d_in[1];   // (64,144,144)
  const float* qkv_w    = (const float*)d_in[2];   // (1536,512)
  const float* qkv_b    = (const float*)d_in[3];   // (1536)
  const float* proj_w   = (const float*)d_in[4];   // (512,512)
  const float* proj_b   = (const float*)d_in[5];   // (512)
  const float* cpb_w1   = (const float*)d_in[6];   // (512,2)
  const float* cpb_b1   = (const float*)d_in[7];   // (512)
  const float* cpb_w2   = (const float*)d_in[8];   // (16,512)
  const float* rel_tab  = (const float*)d_in[9];   // (1,23,23,2) = 529x2
  const int*   rel_idx  = (const int*)d_in[10];    // (144,144)
  float* out = (float*)d_out;

  char* ws = (char*)d_ws;
  unsigned short* x_bf    = (unsigned short*)(ws);                 // 37,748,736 B
  unsigned short* wq_bf   = (unsigned short*)(ws + 37748736);      //  1,572,864 B
  unsigned short* wp_bf   = (unsigned short*)(ws + 39321600);      //    524,288 B
  unsigned short* qkv_ws  = (unsigned short*)(ws + 39845888);      // 113,246,208 B
  unsigned short* attn_ws = (unsigned short*)(ws + 153092096);     // 37,748,736 B
  float*          tbl_ws  = (float*)(ws + 190840832);              //     33,856 B
  float*          bias_ws = (float*)(ws + 190874688);              //  1,327,104 B
  // total 192,201,792 B

  // fp32 -> bf16 conversions
  cvt_f32_bf16<<<2048, 256, 0, stream>>>((const float4*)x, x_bf, 4718592);
  cvt_f32_bf16<<<768, 256, 0, stream>>>((const float4*)qkv_w, wq_bf, 196608);
  cvt_f32_bf16<<<256, 256, 0, stream>>>((const float4*)proj_w, wp_bf, 65536);

  // CPB bias
  cpb_mlp<<<529, 512, 0, stream>>>(rel_tab, cpb_w1, cpb_b1, cpb_w2, tbl_ws);
  bias_gather<<<1296, 256, 0, stream>>>(tbl_ws, rel_idx, bias_ws);

  // QKV GEMM: (36864,512) x (1536,512)^T -> bf16 (36864,1536)
  gemm_bt_k<true><<<dim3(12, 288), 256, 0, stream>>>(x_bf, wq_bf, qkv_b,
                                                     (void*)qkv_ws, 1536, 512);

  // attention: one block per (head, window-batch)
  hipFuncSetAttribute((const void*)attn_k,
                      hipFuncAttributeMaxDynamicSharedMemorySize, 71424);
  attn_k<<<dim3(16, 256), 256, 71424, stream>>>(qkv_ws, mask, bias_ws, attn_ws);

  // proj GEMM: (36864,512) x (512,512)^T -> f32 out
  gemm_bt_k<false><<<dim3(4, 288), 256, 0, stream>>>(attn_ws, wp_bf, proj_b,
                                                     (void*)out, 512, 512);
}